// Round 16
// baseline (274.065 us; speedup 1.0000x reference)
//
#include <hip/hip_runtime.h>
#include <hip/hip_fp16.h>
#include <cstdint>
#include <cstddef>

// Problem constants
#define NB 512
#define NR 1152
#define NC 8
#define NJ 10
#define NO 16
#define NJO 160   // NJ*NO
#define NRC 36    // r-chunks for s0 partials (NR/32)

typedef unsigned int uint32;

union H2U { __half2 h; uint32 u; };

__device__ __forceinline__ uint32 packf16(float a0, float a1) {
    H2U p;
    p.h = __halves2half2(__float2half_rn(a0), __float2half_rn(a1));
    return p.u;
}
__device__ __forceinline__ float2 unpackf16(uint32 w) {
    H2U p; p.u = w;
    return __half22float2(p.h);
}

__device__ __forceinline__ float dot8f(float4 p, float4 q, float4 xa, float4 xb) {
    return p.x * xa.x + p.y * xa.y + p.z * xa.z + p.w * xa.w
         + q.x * xb.x + q.y * xb.y + q.z * xb.z + q.w * xb.w;
}

// ============================================================================
// Kernel 0: transpose x[b][r][c] -> xT[r][b][c]. (R1-exact.)
// ============================================================================
__global__ __launch_bounds__(256) void xpose_kernel(const float* __restrict__ x,
                                                    float* __restrict__ xT) {
    const int r0 = blockIdx.x * 16;
    const int b0 = blockIdx.y * 64;
    const int t  = threadIdx.x;
    __shared__ float tile[16][65][8];

    for (int i = t; i < 2048; i += 256) {
        int b = i >> 5, r = (i >> 1) & 15, h = i & 1;
        float4 v = *(const float4*)&x[(size_t)(b0 + b) * (NR * NC) + (size_t)(r0 + r) * NC + h * 4];
        *(float4*)&tile[r][b][h * 4] = v;
    }
    __syncthreads();
    for (int i = t; i < 2048; i += 256) {
        int r = i >> 7, b = (i >> 1) & 63, h = i & 1;
        float4 v = *(const float4*)&tile[r][b][h * 4];
        *(float4*)&xT[(size_t)(r0 + r) * (NB * NC) + (size_t)(b0 + b) * NC + h * 4] = v;
    }
}

// ============================================================================
// Kernel 1 (R15): uhat main phase (R5-exact octo-grouped layout) + OPTIONAL
// fused s0-partial phase on blocks 0..575.
//
// Routing is BYTES-BOUND (R14: 567 MB logical / 97 us = 5.85 TB/s ~ the
// achievable read BW; all structural experiments null). Only lever = fewer
// bytes: eliminate pass 0 (189 MB) via s0 partials computed here, in the
// shadow of uhat's ~20%-utilized pipes (all 1152 blocks co-resident).
// s0 phase: block bid<576 -> tile (b0s=(bid%16)*32, rc=bid/16); thread owns
// 4jo x 4b (256 LDS b128 reads/thread -- 4x fewer than R6's s0gemm whose
// 1024 reads made it ~52 us). LDS overlaid with main phase's Ws/xs after a
// barrier (max 32 KB -> residency preserved).
// ============================================================================
__global__ __launch_bounds__(320) void uhat_kernel(const float* __restrict__ xT,
                                                   const float* __restrict__ W,
                                                   uint32* __restrict__ u,
                                                   const float* __restrict__ x,
                                                   float* __restrict__ s0p,
                                                   int do_s0) {
    const int r = blockIdx.x;
    const int t = threadIdx.x;

    __shared__ char shm[32768 + 512];   // overlay: phase1 Ws(5248)+xs(16384); phase2 xs2(32768)
    float (*Ws)[NJO + 4] = (float (*)[NJO + 4])shm;            // [NC][164]
    float (*xs)[NC]      = (float (*)[NC])(shm + 5248);        // [NB][8]

    for (int i = t; i < NJO * NC; i += 320) {
        Ws[i & 7][i >> 3] = W[(size_t)r * (NJO * NC) + i];
    }
    {
        const float4* xsrc = (const float4*)(xT + (size_t)r * (NB * NC));
        float4* xdst = (float4*)&xs[0][0];
        for (int i = t; i < (NB * NC) / 4; i += 320) xdst[i] = xsrc[i];
    }
    __syncthreads();

    const int ni   = t % 80;   // u32 slot in the permuted row
    const int half = t / 80;
    {
        const int g    = ni / 10;        // (qt,jh) group
        const int rem  = ni % 10;
        const int qt   = g >> 1;
        const int jh   = g & 1;
        const int j    = jh * 5 + (rem >> 1);
        const int d    = rem & 1;
        const int jo0  = 16 * j + 4 * qt + 2 * d;   // o index pair (jo0, jo0+1)

        float w0[8], w1[8];
#pragma unroll
        for (int c = 0; c < 8; ++c) {
            w0[c] = Ws[c][jo0];
            w1[c] = Ws[c][jo0 + 1];
        }

        for (int b = half; b < NB; b += 4) {
            const float4* xp = (const float4*)xs[b];
            float4 xa = xp[0], xb = xp[1];
            float a0 = w0[0] * xa.x + w0[1] * xa.y + w0[2] * xa.z + w0[3] * xa.w
                     + w0[4] * xb.x + w0[5] * xb.y + w0[6] * xb.z + w0[7] * xb.w;
            float a1 = w1[0] * xa.x + w1[1] * xa.y + w1[2] * xa.z + w1[3] * xa.w
                     + w1[4] * xb.x + w1[5] * xb.y + w1[6] * xb.z + w1[7] * xb.w;
            u[(size_t)(b * NR + r) * 80 + ni] = packf16(a0, a1);
        }
    }

    // ---- phase 2: s0 partials (blocks 0..575 only; block-uniform branch) ----
    if (do_s0 && r < 576) {
        __syncthreads();   // main phase done with Ws/xs; reuse LDS
        float (*xs2)[32][NC] = (float (*)[32][NC])shm;   // [rloc][bloc][c], 32 KB

        const int b0s = (r % 16) * 32;
        const int rc  = r / 16;
        const int r0  = rc * 32;

        for (int i = t; i < 2048; i += 320) {
            int bloc = i >> 6, rloc = (i >> 1) & 31, h = i & 1;
            float4 v = *(const float4*)&x[(size_t)(b0s + bloc) * (NR * NC) + (size_t)(r0 + rloc) * NC + h * 4];
            *(float4*)&xs2[rloc][bloc][h * 4] = v;
        }
        __syncthreads();

        const int joq = t % 40;   // jo quad: jo = 4*joq .. 4*joq+3
        const int bq  = t / 40;   // 0..7 -> b = b0s + bq*4 + {0..3}

        float acc[16];
#pragma unroll
        for (int i = 0; i < 16; ++i) acc[i] = 0.0f;

#pragma unroll 1
        for (int rloc = 0; rloc < 32; ++rloc) {
            const float* wr = W + ((size_t)(r0 + rloc) * NJO + 4 * joq) * NC;
            float4 w0a = *(const float4*)(wr);
            float4 w0b = *(const float4*)(wr + 4);
            float4 w1a = *(const float4*)(wr + 8);
            float4 w1b = *(const float4*)(wr + 12);
            float4 w2a = *(const float4*)(wr + 16);
            float4 w2b = *(const float4*)(wr + 20);
            float4 w3a = *(const float4*)(wr + 24);
            float4 w3b = *(const float4*)(wr + 28);
#pragma unroll
            for (int bb = 0; bb < 4; ++bb) {
                const float* xp = xs2[rloc][bq * 4 + bb];
                float4 xa = *(const float4*)xp;
                float4 xb = *(const float4*)(xp + 4);
                acc[4 * bb + 0] += dot8f(w0a, w0b, xa, xb);
                acc[4 * bb + 1] += dot8f(w1a, w1b, xa, xb);
                acc[4 * bb + 2] += dot8f(w2a, w2b, xa, xb);
                acc[4 * bb + 3] += dot8f(w3a, w3b, xa, xb);
            }
        }

#pragma unroll
        for (int bb = 0; bb < 4; ++bb) {
            float4 st = make_float4(acc[4 * bb + 0], acc[4 * bb + 1],
                                    acc[4 * bb + 2], acc[4 * bb + 3]);
            *(float4*)&s0p[((size_t)rc * NB + (b0s + bq * 4 + bb)) * NJO + 4 * joq] = st;
        }
    }
}

// ============================================================================
// Routing variant A (fallback, R5-exact 3-pass, measured 95.1 us):
// 576 thr, 8 lanes/row, acc[20], depth-1 uint2 ping-pong, VGPR 64.
// ============================================================================
#define LOADROW(Q0, Q1, Q2, Q3, Q4, ROW)                                      \
    {                                                                         \
        const uint32* p_ = ubase + (size_t)(ROW) * 80;                        \
        Q0 = *(const uint2*)(p_);     Q1 = *(const uint2*)(p_ + 2);           \
        Q2 = *(const uint2*)(p_ + 4); Q3 = *(const uint2*)(p_ + 6);           \
        Q4 = *(const uint2*)(p_ + 8);                                         \
    }

#define PROCESS_A(Q0, Q1, Q2, Q3, Q4)                                         \
    {                                                                         \
        uint32 ur[10];                                                        \
        ur[0] = Q0.x; ur[1] = Q0.y; ur[2] = Q1.x; ur[3] = Q1.y;               \
        ur[4] = Q2.x; ur[5] = Q2.y; ur[6] = Q3.x; ur[7] = Q3.y;               \
        ur[8] = Q4.x; ur[9] = Q4.y;                                           \
        float cj[5];                                                          \
        if (it == 0) {                                                        \
            _Pragma("unroll")                                                 \
            for (int jl = 0; jl < 5; ++jl) cj[jl] = 0.1f;                     \
        } else {                                                              \
            float sum = 0.0f;                                                 \
            _Pragma("unroll")                                                 \
            for (int jl = 0; jl < 5; ++jl) {                                  \
                float2 ua = unpackf16(ur[2 * jl]);                            \
                float2 ub = unpackf16(ur[2 * jl + 1]);                        \
                float4 vv = *(const float4*)&vls[vbase + 16 * jl];            \
                float pj = ua.x * vv.x + ua.y * vv.y + ub.x * vv.z + ub.y * vv.w; \
                pj += __shfl_xor(pj, 1);                                      \
                pj += __shfl_xor(pj, 2);                                      \
                float e = __expf(pj);                                         \
                cj[jl] = e;                                                   \
                sum += e;                                                     \
            }                                                                 \
            sum += __shfl_xor(sum, 4);                                        \
            float inv = 1.0f / sum;                                           \
            _Pragma("unroll")                                                 \
            for (int jl = 0; jl < 5; ++jl) cj[jl] *= inv;                     \
        }                                                                     \
        _Pragma("unroll")                                                     \
        for (int jl = 0; jl < 5; ++jl) {                                      \
            float2 ua = unpackf16(ur[2 * jl]);                                \
            float2 ub = unpackf16(ur[2 * jl + 1]);                            \
            acc[4 * jl + 0] += cj[jl] * ua.x;                                 \
            acc[4 * jl + 1] += cj[jl] * ua.y;                                 \
            acc[4 * jl + 2] += cj[jl] * ub.x;                                 \
            acc[4 * jl + 3] += cj[jl] * ub.y;                                 \
        }                                                                     \
    }

__global__ __launch_bounds__(576, 2) void routing3_kernel(const uint32* __restrict__ u,
                                                          float* __restrict__ outp) {
    const int b    = blockIdx.x;
    const int t    = threadIdx.x;
    const int w    = t >> 6;
    const int l    = t & 63;
    const int qt   = l & 3;
    const int jh   = (l >> 2) & 1;
    const int mloc = l >> 3;
    const int g    = qt * 2 + jh;

    __shared__ float sl[NJO];
    __shared__ float vls[NJO];
    __shared__ float vaccl[NJO];

    for (int i = t; i < NJO; i += 576) sl[i] = 0.0f;
    __syncthreads();

    const uint32* ubase = u + (size_t)b * (NR * 80) + g * 10;
    const int vbase = jh * 80 + qt * 4;
    const int rbase = w * 128 + mloc;

#pragma unroll 1
    for (int it = 0; it < 3; ++it) {
        float acc[20];
#pragma unroll
        for (int i = 0; i < 20; ++i) acc[i] = 0.0f;

        uint2 qa0, qa1, qa2, qa3, qa4;
        uint2 qb0, qb1, qb2, qb3, qb4;

        LOADROW(qa0, qa1, qa2, qa3, qa4, rbase)

#pragma unroll 1
        for (int c16 = 0; c16 < 16; c16 += 2) {
            LOADROW(qb0, qb1, qb2, qb3, qb4, rbase + (c16 + 1) * 8)
            PROCESS_A(qa0, qa1, qa2, qa3, qa4)
            if (c16 < 14) {
                LOADROW(qa0, qa1, qa2, qa3, qa4, rbase + (c16 + 2) * 8)
            }
            PROCESS_A(qb0, qb1, qb2, qb3, qb4)
        }

        float a[12];
        {
            const int bit = (l >> 3) & 1;
#pragma unroll
            for (int i = 0; i < 12; ++i) {
                float lo = acc[i];
                float hi = (i + 12 < 20) ? acc[i + 12] : 0.0f;
                float send = bit ? lo : hi;
                float recv = __shfl_xor(send, 8);
                a[i] = (bit ? hi : lo) + recv;
            }
        }
#pragma unroll
        for (int st = 1; st < 3; ++st) {
            const int h = 12 >> st;
            const int bit = (l >> (3 + st)) & 1;
#pragma unroll
            for (int i = 0; i < 6; ++i) {
                if (i < h) {
                    float send = bit ? a[i] : a[i + h];
                    float recv = __shfl_xor(send, 8 << st);
                    a[i] = (bit ? a[i + h] : a[i]) + recv;
                }
            }
        }
        const int base = 3 * (__brev((uint32)mloc) >> 29);
#pragma unroll
        for (int i = 0; i < 3; ++i) {
            int aidx = base + i;
            if (aidx < 20) {
                int jl = aidx >> 2, e = aidx & 3;
                atomicAdd(&sl[16 * (jh * 5 + jl) + 4 * qt + e], a[i]);
            }
        }
        __syncthreads();

        if (t < 80) {
            float2 sv = *(const float2*)&sl[2 * t];
            float sq = sv.x * sv.x + sv.y * sv.y;
#pragma unroll
            for (int off = 1; off < 8; off <<= 1) sq += __shfl_xor(sq, off, 8);
            float scale = (sq / (1.0f + sq)) * rsqrtf(sq + 1e-8f);
            float vx = sv.x * scale, vy = sv.y * scale;
            if (it == 2) {
                *(float2*)&outp[b * NJO + 2 * t] = make_float2(vx, vy);
            } else {
                float2 va;
                if (it == 0) va = make_float2(vx, vy);
                else {
                    va = *(const float2*)&vaccl[2 * t];
                    va.x += vx; va.y += vy;
                }
                *(float2*)&vaccl[2 * t] = va;
                *(float2*)&vls[2 * t]   = va;
            }
        }
        __syncthreads();
        if (it < 2) {
            for (int i = t; i < NJO; i += 576) sl[i] = 0.0f;
            __syncthreads();
        }
    }
}

// ============================================================================
// Routing variant B (R8-exact 2-pass, measured 74.3 us): prologue sums the
// 36 s0p partials -> v0; passes it=1,2 only.
// ============================================================================
#define PROCESS_B(Q0, Q1, Q2, Q3, Q4)                                         \
    {                                                                         \
        uint32 ur[10];                                                        \
        ur[0] = Q0.x; ur[1] = Q0.y; ur[2] = Q1.x; ur[3] = Q1.y;               \
        ur[4] = Q2.x; ur[5] = Q2.y; ur[6] = Q3.x; ur[7] = Q3.y;               \
        ur[8] = Q4.x; ur[9] = Q4.y;                                           \
        float cj[5];                                                          \
        {                                                                     \
            float sum = 0.0f;                                                 \
            _Pragma("unroll")                                                 \
            for (int jl = 0; jl < 5; ++jl) {                                  \
                float2 ua = unpackf16(ur[2 * jl]);                            \
                float2 ub = unpackf16(ur[2 * jl + 1]);                        \
                float4 vv = *(const float4*)&vls[vbase + 16 * jl];            \
                float pj = ua.x * vv.x + ua.y * vv.y + ub.x * vv.z + ub.y * vv.w; \
                pj += __shfl_xor(pj, 1);                                      \
                pj += __shfl_xor(pj, 2);                                      \
                float e = __expf(pj);                                         \
                cj[jl] = e;                                                   \
                sum += e;                                                     \
            }                                                                 \
            sum += __shfl_xor(sum, 4);                                        \
            float inv = 1.0f / sum;                                           \
            _Pragma("unroll")                                                 \
            for (int jl = 0; jl < 5; ++jl) cj[jl] *= inv;                     \
        }                                                                     \
        _Pragma("unroll")                                                     \
        for (int jl = 0; jl < 5; ++jl) {                                      \
            float2 ua = unpackf16(ur[2 * jl]);                                \
            float2 ub = unpackf16(ur[2 * jl + 1]);                            \
            acc[4 * jl + 0] += cj[jl] * ua.x;                                 \
            acc[4 * jl + 1] += cj[jl] * ua.y;                                 \
            acc[4 * jl + 2] += cj[jl] * ub.x;                                 \
            acc[4 * jl + 3] += cj[jl] * ub.y;                                 \
        }                                                                     \
    }

__global__ __launch_bounds__(576, 2) void routing2_kernel(const uint32* __restrict__ u,
                                                          const float* __restrict__ s0p,
                                                          float* __restrict__ outp) {
    const int b    = blockIdx.x;
    const int t    = threadIdx.x;
    const int w    = t >> 6;
    const int l    = t & 63;
    const int qt   = l & 3;
    const int jh   = (l >> 2) & 1;
    const int mloc = l >> 3;
    const int g    = qt * 2 + jh;

    __shared__ float sl[NJO];
    __shared__ float vls[NJO];
    __shared__ float vaccl[NJO];

    for (int i = t; i < NJO; i += 576) sl[i] = 0.0f;

    // ---- prologue: v0 = squash(0.1 * sum_rc s0p[rc][b]) ----
    if (t < 80) {
        float sx = 0.0f, sy = 0.0f;
#pragma unroll 6
        for (int rc = 0; rc < NRC; ++rc) {
            float2 p = *(const float2*)&s0p[((size_t)rc * NB + b) * NJO + 2 * t];
            sx += p.x; sy += p.y;
        }
        sx *= 0.1f; sy *= 0.1f;
        float sq = sx * sx + sy * sy;
#pragma unroll
        for (int off = 1; off < 8; off <<= 1) sq += __shfl_xor(sq, off, 8);
        float scale = (sq / (1.0f + sq)) * rsqrtf(sq + 1e-8f);
        float vx = sx * scale, vy = sy * scale;
        *(float2*)&vaccl[2 * t] = make_float2(vx, vy);
        *(float2*)&vls[2 * t]   = make_float2(vx, vy);
    }
    __syncthreads();

    const uint32* ubase = u + (size_t)b * (NR * 80) + g * 10;
    const int vbase = jh * 80 + qt * 4;
    const int rbase = w * 128 + mloc;

#pragma unroll 1
    for (int it = 1; it < 3; ++it) {
        float acc[20];
#pragma unroll
        for (int i = 0; i < 20; ++i) acc[i] = 0.0f;

        uint2 qa0, qa1, qa2, qa3, qa4;
        uint2 qb0, qb1, qb2, qb3, qb4;

        LOADROW(qa0, qa1, qa2, qa3, qa4, rbase)

#pragma unroll 1
        for (int c16 = 0; c16 < 16; c16 += 2) {
            LOADROW(qb0, qb1, qb2, qb3, qb4, rbase + (c16 + 1) * 8)
            PROCESS_B(qa0, qa1, qa2, qa3, qa4)
            if (c16 < 14) {
                LOADROW(qa0, qa1, qa2, qa3, qa4, rbase + (c16 + 2) * 8)
            }
            PROCESS_B(qb0, qb1, qb2, qb3, qb4)
        }

        float a[12];
        {
            const int bit = (l >> 3) & 1;
#pragma unroll
            for (int i = 0; i < 12; ++i) {
                float lo = acc[i];
                float hi = (i + 12 < 20) ? acc[i + 12] : 0.0f;
                float send = bit ? lo : hi;
                float recv = __shfl_xor(send, 8);
                a[i] = (bit ? hi : lo) + recv;
            }
        }
#pragma unroll
        for (int st = 1; st < 3; ++st) {
            const int h = 12 >> st;
            const int bit = (l >> (3 + st)) & 1;
#pragma unroll
            for (int i = 0; i < 6; ++i) {
                if (i < h) {
                    float send = bit ? a[i] : a[i + h];
                    float recv = __shfl_xor(send, 8 << st);
                    a[i] = (bit ? a[i + h] : a[i]) + recv;
                }
            }
        }
        const int base = 3 * (__brev((uint32)mloc) >> 29);
#pragma unroll
        for (int i = 0; i < 3; ++i) {
            int aidx = base + i;
            if (aidx < 20) {
                int jl = aidx >> 2, e = aidx & 3;
                atomicAdd(&sl[16 * (jh * 5 + jl) + 4 * qt + e], a[i]);
            }
        }
        __syncthreads();

        if (t < 80) {
            float2 sv = *(const float2*)&sl[2 * t];
            float sq = sv.x * sv.x + sv.y * sv.y;
#pragma unroll
            for (int off = 1; off < 8; off <<= 1) sq += __shfl_xor(sq, off, 8);
            float scale = (sq / (1.0f + sq)) * rsqrtf(sq + 1e-8f);
            float vx = sv.x * scale, vy = sv.y * scale;
            if (it == 2) {
                *(float2*)&outp[b * NJO + 2 * t] = make_float2(vx, vy);
            } else {
                float2 va = *(const float2*)&vaccl[2 * t];
                va.x += vx; va.y += vy;
                *(float2*)&vaccl[2 * t] = va;
                *(float2*)&vls[2 * t]   = va;
            }
        }
        __syncthreads();
        if (it < 2) {
            for (int i = t; i < NJO; i += 576) sl[i] = 0.0f;
            __syncthreads();
        }
    }
}

// ============================================================================
// Host: runtime ws_size check. Room for s0p (+11.8 MB) -> fused s0 + 2-pass
// routing (predicted ~195-203 total). No room -> R5-exact path (210.9, safe).
// ============================================================================
extern "C" void kernel_launch(void* const* d_in, const int* in_sizes, int n_in,
                              void* d_out, int out_size, void* d_ws, size_t ws_size,
                              hipStream_t stream) {
    (void)in_sizes; (void)n_in; (void)out_size;

    const float* x = (const float*)d_in[0];  // [B,R,C]
    const float* W = (const float*)d_in[1];  // [R,J,O,C]
    float* out = (float*)d_out;              // [B,J,O,1] fp32

    char* ws = (char*)d_ws;
    const size_t XBYTES  = (size_t)NR * NB * NC * 4;        // 18,874,368
    const size_t UBYTES  = (size_t)NB * NR * 80 * 4;        // 188,743,680
    const size_t S0PBYTES = (size_t)NRC * NB * NJO * 4;     // 11,796,480
    float*  xT  = (float*)ws;
    uint32* u   = (uint32*)(ws + XBYTES);                   // [B,R,80] f16 pairs
    float*  s0p = (float*)(ws + XBYTES + UBYTES);           // [36][B][160] fp32

    const bool room = (ws_size >= XBYTES + UBYTES + S0PBYTES);

    xpose_kernel<<<dim3(NR / 16, NB / 64), 256, 0, stream>>>(x, xT);
    uhat_kernel<<<NR, 320, 0, stream>>>(xT, W, u, x, s0p, room ? 1 : 0);
    if (room) {
        routing2_kernel<<<NB, 576, 0, stream>>>(u, s0p, out);
    } else {
        routing3_kernel<<<NB, 576, 0, stream>>>(u, out);
    }
}

// Round 17
// 214.293 us; speedup vs baseline: 1.2789x; 1.2789x over previous
//
#include <hip/hip_runtime.h>
#include <hip/hip_fp16.h>
#include <cstdint>
#include <cstddef>

// Problem constants
#define NB 512
#define NR 1152
#define NC 8
#define NJ 10
#define NO 16
#define NJO 160   // NJ*NO

typedef unsigned int uint32;

union H2U { __half2 h; uint32 u; };

__device__ __forceinline__ uint32 packf16(float a0, float a1) {
    H2U p;
    p.h = __halves2half2(__float2half_rn(a0), __float2half_rn(a1));
    return p.u;
}
__device__ __forceinline__ float2 unpackf16(uint32 w) {
    H2U p; p.u = w;
    return __half22float2(p.h);
}

// ============================================================================
// Kernel 0: transpose x[b][r][c] -> xT[r][b][c]. (R1-exact.)
// ============================================================================
__global__ __launch_bounds__(256) void xpose_kernel(const float* __restrict__ x,
                                                    float* __restrict__ xT) {
    const int r0 = blockIdx.x * 16;
    const int b0 = blockIdx.y * 64;
    const int t  = threadIdx.x;
    __shared__ float tile[16][65][8];

    for (int i = t; i < 2048; i += 256) {
        int b = i >> 5, r = (i >> 1) & 15, h = i & 1;
        float4 v = *(const float4*)&x[(size_t)(b0 + b) * (NR * NC) + (size_t)(r0 + r) * NC + h * 4];
        *(float4*)&tile[r][b][h * 4] = v;
    }
    __syncthreads();
    for (int i = t; i < 2048; i += 256) {
        int r = i >> 7, b = (i >> 1) & 63, h = i & 1;
        float4 v = *(const float4*)&tile[r][b][h * 4];
        *(float4*)&xT[(size_t)(r0 + r) * (NB * NC) + (size_t)(b0 + b) * NC + h * 4] = v;
    }
}

// ============================================================================
// Kernel 1: u_hat -> f16 pairs. OCTO-GROUPED rows (R5-exact).
// Row (b,r) = 80 u32; slot ni = g*10 + 2*jloc + d, g = qt*2 + jh,
// j = jh*5 + jloc, holds o-pair (4qt+2d, 4qt+2d+1) of capsule j.
// ============================================================================
__global__ __launch_bounds__(320) void uhat_kernel(const float* __restrict__ xT,
                                                   const float* __restrict__ W,
                                                   uint32* __restrict__ u) {
    const int r = blockIdx.x;
    const int t = threadIdx.x;

    __shared__ float Ws[NC][NJO + 4];   // stride 164: staging conflict-free
    __shared__ float xs[NB][NC];

    for (int i = t; i < NJO * NC; i += 320) {
        Ws[i & 7][i >> 3] = W[(size_t)r * (NJO * NC) + i];
    }
    {
        const float4* xsrc = (const float4*)(xT + (size_t)r * (NB * NC));
        float4* xdst = (float4*)&xs[0][0];
        for (int i = t; i < (NB * NC) / 4; i += 320) xdst[i] = xsrc[i];
    }
    __syncthreads();

    const int ni   = t % 80;   // u32 slot in the permuted row
    const int half = t / 80;
    const int g    = ni / 10;        // (qt,jh) group
    const int rem  = ni % 10;
    const int qt   = g >> 1;
    const int jh   = g & 1;
    const int j    = jh * 5 + (rem >> 1);
    const int d    = rem & 1;
    const int jo0  = 16 * j + 4 * qt + 2 * d;   // o index pair (jo0, jo0+1)

    float w0[8], w1[8];
#pragma unroll
    for (int c = 0; c < 8; ++c) {
        w0[c] = Ws[c][jo0];
        w1[c] = Ws[c][jo0 + 1];
    }

    for (int b = half; b < NB; b += 4) {
        const float4* xp = (const float4*)xs[b];
        float4 xa = xp[0], xb = xp[1];
        float a0 = w0[0] * xa.x + w0[1] * xa.y + w0[2] * xa.z + w0[3] * xa.w
                 + w0[4] * xb.x + w0[5] * xb.y + w0[6] * xb.z + w0[7] * xb.w;
        float a1 = w1[0] * xa.x + w1[1] * xa.y + w1[2] * xa.z + w1[3] * xa.w
                 + w1[4] * xb.x + w1[5] * xb.y + w1[6] * xb.z + w1[7] * xb.w;
        u[(size_t)(b * NR + r) * 80 + ni] = packf16(a0, a1);
    }
}

// ============================================================================
// Merged routing kernel (R5-exact, measured 95.1 us / total 210.9 -- session
// best). 576 thr, 8 lanes/row (qt = l&3, jh = (l>>2)&1, mloc = l>>3),
// acc[20], depth-1 uint2 ping-pong (VGPR 64, no spill).
// Post-session verdict: routing is BYTES-BOUND -- 567 MB logical reads in
// 95 us = 5.85 TB/s ~ 93% of achievable read BW. ILP (R5), 2x TLP (R13),
// max occupancy (R13), wave-contiguous layout (R14) all null; 2-pass via
// precomputed s0 saves 21 us but every s0 implementation costs >=50 us
// (R6/R8/R15). This configuration is the structural optimum.
// ============================================================================
#define LOADROW(Q0, Q1, Q2, Q3, Q4, ROW)                                      \
    {                                                                         \
        const uint32* p_ = ubase + (size_t)(ROW) * 80;                        \
        Q0 = *(const uint2*)(p_);     Q1 = *(const uint2*)(p_ + 2);           \
        Q2 = *(const uint2*)(p_ + 4); Q3 = *(const uint2*)(p_ + 6);           \
        Q4 = *(const uint2*)(p_ + 8);                                         \
    }

#define PROCESS(Q0, Q1, Q2, Q3, Q4)                                           \
    {                                                                         \
        uint32 ur[10];                                                        \
        ur[0] = Q0.x; ur[1] = Q0.y; ur[2] = Q1.x; ur[3] = Q1.y;               \
        ur[4] = Q2.x; ur[5] = Q2.y; ur[6] = Q3.x; ur[7] = Q3.y;               \
        ur[8] = Q4.x; ur[9] = Q4.y;                                           \
        float cj[5];                                                          \
        if (it == 0) {                                                        \
            _Pragma("unroll")                                                 \
            for (int jl = 0; jl < 5; ++jl) cj[jl] = 0.1f;                     \
        } else {                                                              \
            float sum = 0.0f;                                                 \
            _Pragma("unroll")                                                 \
            for (int jl = 0; jl < 5; ++jl) {                                  \
                float2 ua = unpackf16(ur[2 * jl]);                            \
                float2 ub = unpackf16(ur[2 * jl + 1]);                        \
                float4 vv = *(const float4*)&vls[vbase + 16 * jl];            \
                float pj = ua.x * vv.x + ua.y * vv.y + ub.x * vv.z + ub.y * vv.w; \
                pj += __shfl_xor(pj, 1);                                      \
                pj += __shfl_xor(pj, 2);                                      \
                float e = __expf(pj);                                         \
                cj[jl] = e;                                                   \
                sum += e;                                                     \
            }                                                                 \
            sum += __shfl_xor(sum, 4);                                        \
            float inv = 1.0f / sum;                                           \
            _Pragma("unroll")                                                 \
            for (int jl = 0; jl < 5; ++jl) cj[jl] *= inv;                     \
        }                                                                     \
        _Pragma("unroll")                                                     \
        for (int jl = 0; jl < 5; ++jl) {                                      \
            float2 ua = unpackf16(ur[2 * jl]);                                \
            float2 ub = unpackf16(ur[2 * jl + 1]);                            \
            acc[4 * jl + 0] += cj[jl] * ua.x;                                 \
            acc[4 * jl + 1] += cj[jl] * ua.y;                                 \
            acc[4 * jl + 2] += cj[jl] * ub.x;                                 \
            acc[4 * jl + 3] += cj[jl] * ub.y;                                 \
        }                                                                     \
    }

__global__ __launch_bounds__(576, 2) void routing_kernel(const uint32* __restrict__ u,
                                                         float* __restrict__ outp) {
    const int b    = blockIdx.x;
    const int t    = threadIdx.x;
    const int w    = t >> 6;          // wave 0..8
    const int l    = t & 63;
    const int qt   = l & 3;           // o-quarter
    const int jh   = (l >> 2) & 1;    // capsule half
    const int mloc = l >> 3;          // row within 8-group
    const int g    = qt * 2 + jh;     // u32-group in row

    __shared__ float sl[NJO];     // s accumulator
    __shared__ float vls[NJO];    // current v-sum (fp32), read by dot
    __shared__ float vaccl[NJO];  // running v0+v1 (fp32)

    for (int i = t; i < NJO; i += 576) sl[i] = 0.0f;
    __syncthreads();

    const uint32* ubase = u + (size_t)b * (NR * 80) + g * 10;
    const int vbase = jh * 80 + qt * 4;     // vls[16*(jh*5+jl) + 4*qt]
    const int rbase = w * 128 + mloc;       // row(c16) = rbase + c16*8

#pragma unroll 1
    for (int it = 0; it < 3; ++it) {
        float acc[20];
#pragma unroll
        for (int i = 0; i < 20; ++i) acc[i] = 0.0f;

        uint2 qa0, qa1, qa2, qa3, qa4;
        uint2 qb0, qb1, qb2, qb3, qb4;

        LOADROW(qa0, qa1, qa2, qa3, qa4, rbase)

#pragma unroll 1
        for (int c16 = 0; c16 < 16; c16 += 2) {
            LOADROW(qb0, qb1, qb2, qb3, qb4, rbase + (c16 + 1) * 8)
            PROCESS(qa0, qa1, qa2, qa3, qa4)
            if (c16 < 14) {
                LOADROW(qa0, qa1, qa2, qa3, qa4, rbase + (c16 + 2) * 8)
            }
            PROCESS(qb0, qb1, qb2, qb3, qb4)
        }

        // ---- reduce-scatter among the 8 same-(qt,jh) lanes (masks 8,16,32) ----
        float a[12];
        {
            const int bit = (l >> 3) & 1;
#pragma unroll
            for (int i = 0; i < 12; ++i) {
                float lo = acc[i];
                float hi = (i + 12 < 20) ? acc[i + 12] : 0.0f;
                float send = bit ? lo : hi;
                float recv = __shfl_xor(send, 8);
                a[i] = (bit ? hi : lo) + recv;
            }
        }
#pragma unroll
        for (int st = 1; st < 3; ++st) {
            const int h = 12 >> st;              // 6,3
            const int bit = (l >> (3 + st)) & 1;
#pragma unroll
            for (int i = 0; i < 6; ++i) {
                if (i < h) {
                    float send = bit ? a[i] : a[i + h];
                    float recv = __shfl_xor(send, 8 << st);
                    a[i] = (bit ? a[i + h] : a[i]) + recv;
                }
            }
        }
        const int base = 3 * (__brev((uint32)mloc) >> 29);
#pragma unroll
        for (int i = 0; i < 3; ++i) {
            int aidx = base + i;
            if (aidx < 20) {
                int jl = aidx >> 2, e = aidx & 3;
                atomicAdd(&sl[16 * (jh * 5 + jl) + 4 * qt + e], a[i]);
            }
        }
        __syncthreads();

        // ---- in-block squash: thread p<80 owns o-pair (2p, 2p+1) ----
        if (t < 80) {
            float2 sv = *(const float2*)&sl[2 * t];
            float sq = sv.x * sv.x + sv.y * sv.y;
#pragma unroll
            for (int off = 1; off < 8; off <<= 1) sq += __shfl_xor(sq, off, 8);
            float scale = (sq / (1.0f + sq)) * rsqrtf(sq + 1e-8f);
            float vx = sv.x * scale, vy = sv.y * scale;
            if (it == 2) {
                *(float2*)&outp[b * NJO + 2 * t] = make_float2(vx, vy);
            } else {
                float2 va;
                if (it == 0) va = make_float2(vx, vy);
                else {
                    va = *(const float2*)&vaccl[2 * t];
                    va.x += vx; va.y += vy;
                }
                *(float2*)&vaccl[2 * t] = va;
                *(float2*)&vls[2 * t]   = va;
            }
        }
        __syncthreads();
        if (it < 2) {
            for (int i = t; i < NJO; i += 576) sl[i] = 0.0f;
            __syncthreads();
        }
    }
}

// ============================================================================
extern "C" void kernel_launch(void* const* d_in, const int* in_sizes, int n_in,
                              void* d_out, int out_size, void* d_ws, size_t ws_size,
                              hipStream_t stream) {
    (void)in_sizes; (void)n_in; (void)out_size; (void)ws_size;

    const float* x = (const float*)d_in[0];  // [B,R,C]
    const float* W = (const float*)d_in[1];  // [R,J,O,C]
    float* out = (float*)d_out;              // [B,J,O,1] fp32

    char* ws = (char*)d_ws;
    const size_t XBYTES = (size_t)NR * NB * NC * 4;   // 18,874,368
    float*  xT = (float*)ws;
    uint32* u  = (uint32*)(ws + XBYTES);              // [B,R,80] f16 pairs

    xpose_kernel<<<dim3(NR / 16, NB / 64), 256, 0, stream>>>(x, xT);
    uhat_kernel<<<NR, 320, 0, stream>>>(xT, W, u);
    routing_kernel<<<NB, 576, 0, stream>>>(u, out);
}